// Round 13
// baseline (99.003 us; speedup 1.0000x reference)
//
#include <hip/hip_runtime.h>

typedef float  f32x4  __attribute__((ext_vector_type(4)));
typedef short  s16x8  __attribute__((ext_vector_type(8)));
typedef short  s16x4  __attribute__((ext_vector_type(4)));

__device__ __forceinline__ unsigned short f2bf(float f) {
    unsigned int u = __float_as_uint(f);
    return (unsigned short)((u + 0x7FFFu + ((u >> 16) & 1u)) >> 16);
}

__device__ __forceinline__ s16x8 cvt8(f32x4 a, f32x4 b) {
    union { unsigned int u[4]; s16x8 v; } r;
    asm("v_cvt_pk_bf16_f32 %0, %1, %2" : "=v"(r.u[0]) : "v"(a[0]), "v"(a[1]));
    asm("v_cvt_pk_bf16_f32 %0, %1, %2" : "=v"(r.u[1]) : "v"(a[2]), "v"(a[3]));
    asm("v_cvt_pk_bf16_f32 %0, %1, %2" : "=v"(r.u[2]) : "v"(b[0]), "v"(b[1]));
    asm("v_cvt_pk_bf16_f32 %0, %1, %2" : "=v"(r.u[3]) : "v"(b[2]), "v"(b[3]));
    return r.v;
}

// non-temporal f32x4 load: x is use-once streaming data — keep it from
// thrashing L2 so wt3 stays L2-resident (the round-12 diagnosis).
__device__ __forceinline__ f32x4 ntl4(const float* p) {
    return __builtin_nontemporal_load((const f32x4*)p);
}

// lgkm-only barrier (vmcnt stays in flight)
__device__ __forceinline__ void lds_barrier() {
    asm volatile("s_waitcnt lgkmcnt(0)" ::: "memory");
    __builtin_amdgcn_s_barrier();
    asm volatile("" ::: "memory");
}

// ---------------------------------------------------------------------------
// Kernel 0: wt3 = FRAGMENT-MAJOR bf16 weights (verified R9/R11).
// Fragment (n16,ks,kkk) = one wave's exact MFMA B-operand (64 lanes x 16B):
// value = W_sel[k][n&127], n = n16*16 + (lane&15),
// k = ks*64 + kkk*32 + (lane>>4)*8 + j; byte = fragid*1024 + lane*16 + j*2.
// ---------------------------------------------------------------------------
__global__ void prep_wt(const float* __restrict__ Wq,
                        const float* __restrict__ Wk,
                        const float* __restrict__ Wv,
                        unsigned char* __restrict__ wt3) {
    int n = blockIdx.x;                       // 0..383
    const float* W = (n < 128) ? Wq : ((n < 256) ? Wk : Wv);
    int h = n & 127;
    int n16 = n >> 4, lmn = n & 15;
    for (int k = threadIdx.x; k < 1024; k += blockDim.x) {
        unsigned short v = f2bf(W[(size_t)k * 128 + h]);
        int ks = k >> 6, rem = k & 63;
        int kkk = rem >> 5, l4_ = (rem >> 3) & 3, j = rem & 7;
        int lane = l4_ * 16 + lmn;
        size_t off = (size_t)(n16 * 32 + ks * 2 + kkk) * 1024 + lane * 16 + j * 2;
        *(unsigned short*)(wt3 + off) = v;
    }
}

// ---------------------------------------------------------------------------
// Kernel 1: QKV GEMM — R11 structure (best: ~67µs) + NON-TEMPORAL x loads.
// Theory: x streaming (16MB per XCD) thrashed the 4MB L2, so every B
// refetch (196MB) was served from L3 at 600-900cy latency — the shared
// bottleneck of all 8 previous schedules.  `nt` x-loads leave wt3 (768KB)
// L2-resident; B becomes ~200cy L2 hits covered by the existing half-tile
// prefetch distance.  Everything else identical to R11: BM=128, BN=384,
// grid 256, 8 waves 1M x 8N (acc[8][3]), B wave-private regs from
// fragment-major wt3 (compiler-counted waits), A-only LDS 2x16KB swizzled
// dbuf, ONE lgkm-only barrier/tile.
// Outputs: Q,K bf16 [B*T][128]; V transposed bf16 [B][128][256].
// ---------------------------------------------------------------------------
__global__ __launch_bounds__(512, 2) void qkv_gemm(
    const float* __restrict__ x,
    const unsigned char* __restrict__ wt3,
    unsigned short* __restrict__ qo,
    unsigned short* __restrict__ ko,
    unsigned short* __restrict__ vto) {

    __shared__ char smem[32768];              // A: 2 x [128][128B] swizzled

    const int tid = threadIdx.x;
    const int bm  = blockIdx.x;               // 0..255 (M tiles of 128)
    const int lane = tid & 63, wid = tid >> 6;
    const int lm = lane & 15, l4 = lane >> 4;

    f32x4 acc[8][3];
#pragma unroll
    for (int i = 0; i < 8; ++i)
#pragma unroll
        for (int j = 0; j < 3; ++j) acc[i][j] = (f32x4)0.f;

    // ---- A staging: thread -> row tid>>2, 16 consecutive f32 ----
    const int ar  = tid >> 2;                 // 0..127
    const int acb = (tid & 3) * 16;
    const float* xp = x + (size_t)(bm * 128 + ar) * 1024 + acb;
    const int aswz = (ar & 7) << 4;
    const int aw0 = ar * 128 + ((acb * 2) ^ aswz);
    const int aw1 = ar * 128 + ((acb * 2 + 16) ^ aswz);

    // ---- B fragment pointers (wave-private) ----
    const unsigned char* wb = wt3 + (size_t)lane * 16;
    const unsigned char* wbq[3];
#pragma unroll
    for (int ni = 0; ni < 3; ++ni) wbq[ni] = wb + (size_t)(wid * 3 + ni) * 32768;

    int arow[8];
#pragma unroll
    for (int mi = 0; mi < 8; ++mi) arow[mi] = mi * 16 + lm;

    s16x8 af[8];
    s16x8 bqE0[3], bqE1[3], bqO0[3], bqO1[3];
    f32x4 pa0, pa1, pa2, pa3;

#define AFREAD(AB, KOFF)                                                       \
    do {                                                                       \
        _Pragma("unroll")                                                      \
        for (int mi = 0; mi < 8; ++mi)                                         \
            af[mi] = *(const s16x8*)(smem + (AB) + arow[mi] * 128 +            \
                      (((KOFF) + l4 * 16) ^ ((arow[mi] & 7) << 4)));           \
    } while (0)

#define MFMA3(BQ)                                                              \
    do {                                                                       \
        __builtin_amdgcn_s_setprio(1);                                         \
        _Pragma("unroll")                                                      \
        for (int ni = 0; ni < 3; ++ni)                                         \
            _Pragma("unroll")                                                  \
            for (int mi = 0; mi < 8; ++mi)                                     \
                acc[mi][ni] = __builtin_amdgcn_mfma_f32_16x16x32_bf16(         \
                    af[mi], (BQ)[ni], acc[mi][ni], 0, 0, 0);                   \
        __builtin_amdgcn_s_setprio(0);                                         \
    } while (0)

    // ---- prologue: A(0)->LDS buf0, B(0)->bqE, pa=A(1) ----
    {
        f32x4 a0 = ntl4(xp);
        f32x4 a1 = ntl4(xp + 4);
        f32x4 a2 = ntl4(xp + 8);
        f32x4 a3 = ntl4(xp + 12);
#pragma unroll
        for (int ni = 0; ni < 3; ++ni) {
            bqE0[ni] = *(const s16x8*)(wbq[ni]);
            bqE1[ni] = *(const s16x8*)(wbq[ni] + 1024);
        }
        *(s16x8*)(smem + aw0) = cvt8(a0, a1);
        *(s16x8*)(smem + aw1) = cvt8(a2, a3);
        pa0 = ntl4(xp + 64);
        pa1 = ntl4(xp + 68);
        pa2 = ntl4(xp + 72);
        pa3 = ntl4(xp + 76);
        lds_barrier();
    }

    for (int tp = 0; tp < 8; ++tp) {
        const int t = tp * 2;
        // ============ EVEN tile t (A buf0) ============
        AFREAD(0, 0);
        MFMA3(bqE0);
        // issue B(t+1) kkk0 (used next tile start)
#pragma unroll
        for (int ni = 0; ni < 3; ++ni)
            bqO0[ni] = *(const s16x8*)(wbq[ni] + (t + 1) * 2048);
        AFREAD(0, 64);
        MFMA3(bqE1);
#pragma unroll
        for (int ni = 0; ni < 3; ++ni)
            bqO1[ni] = *(const s16x8*)(wbq[ni] + (t + 1) * 2048 + 1024);
        // stage A(t+1) -> buf1; pa = A(t+2)
        *(s16x8*)(smem + 16384 + aw0) = cvt8(pa0, pa1);
        *(s16x8*)(smem + 16384 + aw1) = cvt8(pa2, pa3);
        if (tp < 7) {
            const float* xq = xp + (t + 2) * 64;
            pa0 = ntl4(xq);
            pa1 = ntl4(xq + 4);
            pa2 = ntl4(xq + 8);
            pa3 = ntl4(xq + 12);
        }
        lds_barrier();

        // ============ ODD tile t+1 (A buf1) ============
        AFREAD(16384, 0);
        MFMA3(bqO0);
        if (tp < 7) {
#pragma unroll
            for (int ni = 0; ni < 3; ++ni)
                bqE0[ni] = *(const s16x8*)(wbq[ni] + (t + 2) * 2048);
        }
        AFREAD(16384, 64);
        MFMA3(bqO1);
        if (tp < 7) {
#pragma unroll
            for (int ni = 0; ni < 3; ++ni)
                bqE1[ni] = *(const s16x8*)(wbq[ni] + (t + 2) * 2048 + 1024);
            // stage A(t+2) -> buf0; pa = A(t+3)
            *(s16x8*)(smem + aw0) = cvt8(pa0, pa1);
            *(s16x8*)(smem + aw1) = cvt8(pa2, pa3);
            const float* xq = xp + (t + 3) * 64;
            pa0 = ntl4(xq);
            pa1 = ntl4(xq + 4);
            pa2 = ntl4(xq + 8);
            pa3 = ntl4(xq + 12);
            lds_barrier();
        }
    }

#undef AFREAD
#undef MFMA3

    // ---- epilogue (layout verified R6-R12) ----
#pragma unroll
    for (int mi = 0; mi < 8; ++mi) {
        int m0 = bm * 128 + mi * 16 + l4 * 4;  // global row (j adds 0..3)
#pragma unroll
        for (int ni = 0; ni < 3; ++ni) {
            int nb  = wid * 48 + ni * 16;
            int mat = nb >> 7;                 // 0=Q 1=K 2=V
            int col = (nb & 127) + lm;
            if (mat == 2) {
                int bb2 = m0 >> 8, tt = m0 & 255;
                s16x4 w4;
#pragma unroll
                for (int j = 0; j < 4; ++j) w4[j] = (short)f2bf(acc[mi][ni][j]);
                *(s16x4*)(vto + ((size_t)bb2 * 128 + col) * 256 + tt) = w4;
            } else {
                unsigned short* dst = (mat == 0) ? qo : ko;
#pragma unroll
                for (int j = 0; j < 4; ++j)
                    dst[(size_t)(m0 + j) * 128 + col] = f2bf(acc[mi][ni][j]);
            }
        }
    }
}

// ---------------------------------------------------------------------------
// Kernel 2: causal attention (unchanged, verified; ~7µs).
// ---------------------------------------------------------------------------
__global__ __launch_bounds__(512) void attn(
    const unsigned short* __restrict__ q,
    const unsigned short* __restrict__ k,
    const unsigned short* __restrict__ vt,
    float* __restrict__ out) {

    __shared__ char pbuf[65536];               // 8 waves x [16][256] bf16

    const int tid = threadIdx.x, wid = tid >> 6, lane = tid & 63;
    const int lm = lane & 15, l4 = lane >> 4;
    const int b = blockIdx.x >> 1, qt = blockIdx.x & 1;
    const int qbase = qt << 7;
    const int t0 = qbase + wid * 16;
    const int nfrags = (qbase + 128) >> 4;
    const int nkf    = (qbase + 128) >> 5;

    const unsigned short* qrow = q + (size_t)(b * 256 + t0 + lm) * 128 + l4 * 8;
    s16x8 qf[4];
#pragma unroll
    for (int kf = 0; kf < 4; ++kf) qf[kf] = *(const s16x8*)(qrow + kf * 32);

    f32x4 sacc[16];
#pragma unroll
    for (int i = 0; i < 16; ++i) sacc[i] = (f32x4)0.f;

    const unsigned short* kbase = k + (size_t)(b * 256) * 128 + l4 * 8;
#pragma unroll
    for (int nf = 0; nf < 16; ++nf) {
        if (nf < nfrags) {
#pragma unroll
            for (int kf = 0; kf < 4; ++kf) {
                s16x8 a = *(const s16x8*)(kbase + (size_t)(nf * 16 + lm) * 128 + kf * 32);
                sacc[nf] = __builtin_amdgcn_mfma_f32_16x16x32_bf16(a, qf[kf], sacc[nf], 0, 0, 0);
            }
        }
    }

    const float scale = 0.08838834764831845f;  // 1/sqrt(128)
    const int tg = t0 + lm;
    float mx = -1e30f;
#pragma unroll
    for (int nf = 0; nf < 16; ++nf) {
        if (nf < nfrags) {
#pragma unroll
            for (int j = 0; j < 4; ++j) {
                int kv = nf * 16 + l4 * 4 + j;
                float s = sacc[nf][j] * scale;
                s = (kv > tg) ? -1e30f : s;
                sacc[nf][j] = s;
                mx = fmaxf(mx, s);
            }
        }
    }
    mx = fmaxf(mx, __shfl_xor(mx, 16));
    mx = fmaxf(mx, __shfl_xor(mx, 32));
    float sum = 0.f;
#pragma unroll
    for (int nf = 0; nf < 16; ++nf) {
        if (nf < nfrags) {
#pragma unroll
            for (int j = 0; j < 4; ++j) {
                float p = __expf(sacc[nf][j] - mx);
                sacc[nf][j] = p;
                sum += p;
            }
        }
    }
    sum += __shfl_xor(sum, 16);
    sum += __shfl_xor(sum, 32);
    float rinv = 1.0f / sum;

    char* pw = pbuf + wid * 8192 + lm * 512;
#pragma unroll
    for (int nf = 0; nf < 16; ++nf) {
        if (nf < nfrags) {
            s16x4 w;
#pragma unroll
            for (int j = 0; j < 4; ++j) w[j] = (short)f2bf(sacc[nf][j] * rinv);
            *(s16x4*)(pw + ((nf * 32 + l4 * 8) ^ ((lm & 7) << 4))) = w;
        }
    }
    asm volatile("s_waitcnt lgkmcnt(0)" ::: "memory");

    f32x4 oacc[8];
#pragma unroll
    for (int i = 0; i < 8; ++i) oacc[i] = (f32x4)0.f;

    const unsigned short* vbase = vt + (size_t)b * 32768 + l4 * 8;
#pragma unroll
    for (int kvf = 0; kvf < 8; ++kvf) {
        if (kvf < nkf) {
            s16x8 pf = *(const s16x8*)(pbuf + wid * 8192 + lm * 512 +
                        ((kvf * 64 + l4 * 16) ^ ((lm & 7) << 4)));
#pragma unroll
            for (int hf = 0; hf < 8; ++hf) {
                s16x8 a = *(const s16x8*)(vbase + (size_t)(hf * 16 + lm) * 256 + kvf * 32);
                oacc[hf] = __builtin_amdgcn_mfma_f32_16x16x32_bf16(a, pf, oacc[hf], 0, 0, 0);
            }
        }
    }

    float* ob = out + (size_t)(b * 256 + t0 + lm) * 128 + l4 * 4;
#pragma unroll
    for (int hf = 0; hf < 8; ++hf)
        *(f32x4*)(ob + hf * 16) = oacc[hf];
}

// ---------------------------------------------------------------------------
extern "C" void kernel_launch(void* const* d_in, const int* in_sizes, int n_in,
                              void* d_out, int out_size, void* d_ws, size_t ws_size,
                              hipStream_t stream) {
    const float* x  = (const float*)d_in[0];
    const float* Wq = (const float*)d_in[1];
    const float* Wk = (const float*)d_in[2];
    const float* Wv = (const float*)d_in[3];
    float* out = (float*)d_out;

    char* ws = (char*)d_ws;
    unsigned char*  wt = (unsigned char*)(ws);                     // 786432 B (fragment-major)
    unsigned short* qb = (unsigned short*)(ws + 786432);
    unsigned short* kb = (unsigned short*)(ws + 786432 + 8388608);
    unsigned short* vb = (unsigned short*)(ws + 786432 + 2 * 8388608);

    prep_wt<<<384, 256, 0, stream>>>(Wq, Wk, Wv, wt);
    qkv_gemm<<<256, 512, 0, stream>>>(x, wt, qb, kb, vb);
    attn<<<256, 512, 0, stream>>>(qb, kb, vb, out);
}

// Round 15
// 88.335 us; speedup vs baseline: 1.1208x; 1.1208x over previous
//
#include <hip/hip_runtime.h>

typedef float  f32x4  __attribute__((ext_vector_type(4)));
typedef short  s16x8  __attribute__((ext_vector_type(8)));
typedef short  s16x4  __attribute__((ext_vector_type(4)));

__device__ __forceinline__ unsigned short f2bf(float f) {
    unsigned int u = __float_as_uint(f);
    return (unsigned short)((u + 0x7FFFu + ((u >> 16) & 1u)) >> 16);
}

__device__ __forceinline__ s16x8 cvt8(f32x4 a, f32x4 b) {
    union { unsigned int u[4]; s16x8 v; } r;
    asm("v_cvt_pk_bf16_f32 %0, %1, %2" : "=v"(r.u[0]) : "v"(a[0]), "v"(a[1]));
    asm("v_cvt_pk_bf16_f32 %0, %1, %2" : "=v"(r.u[1]) : "v"(a[2]), "v"(a[3]));
    asm("v_cvt_pk_bf16_f32 %0, %1, %2" : "=v"(r.u[2]) : "v"(b[0]), "v"(b[1]));
    asm("v_cvt_pk_bf16_f32 %0, %1, %2" : "=v"(r.u[3]) : "v"(b[2]), "v"(b[3]));
    return r.v;
}

#define GLOAD_LDS16(g, l) __builtin_amdgcn_global_load_lds(                    \
    (const __attribute__((address_space(1))) void*)(g),                        \
    (__attribute__((address_space(3))) void*)(l), 16, 0, 0)

// ---------------------------------------------------------------------------
// Kernel 0: wt3 = FRAGMENT-MAJOR bf16 weights (verified R9/R11/R12).
// Fragment (n16,ks,kkk) = one wave's exact MFMA B-operand (64 lanes x 16B):
// value = W_sel[k][n&127], n = n16*16 + (lane&15),
// k = ks*64 + kkk*32 + (lane>>4)*8 + j; byte = fragid*1024 + lane*16 + j*2.
// ---------------------------------------------------------------------------
__global__ void prep_wt(const float* __restrict__ Wq,
                        const float* __restrict__ Wk,
                        const float* __restrict__ Wv,
                        unsigned char* __restrict__ wt3) {
    int n = blockIdx.x;                       // 0..383
    const float* W = (n < 128) ? Wq : ((n < 256) ? Wk : Wv);
    int h = n & 127;
    int n16 = n >> 4, lmn = n & 15;
    for (int k = threadIdx.x; k < 1024; k += blockDim.x) {
        unsigned short v = f2bf(W[(size_t)k * 128 + h]);
        int ks = k >> 6, rem = k & 63;
        int kkk = rem >> 5, l4_ = (rem >> 3) & 3, j = rem & 7;
        int lane = l4_ * 16 + lmn;
        size_t off = (size_t)(n16 * 32 + ks * 2 + kkk) * 1024 + lane * 16 + j * 2;
        *(unsigned short*)(wt3 + off) = v;
    }
}

// ---------------------------------------------------------------------------
// Kernel 1: QKV GEMM — NOTHING on the barrier path (R14 structure, with the
// missing bm*128 source-offset bug fixed).
// A goes global->LDS as RAW F32 via global_load_lds, issued 2 tiles ahead
// into a 4x32KB ring; f32->bf16 conversion at fragment-read time (2
// ds_read_b128 + 4 cvt_pk, off the sync path).  gload_lds needs a linear
// LDS dest, so the SOURCE lane->chunk map is XOR-permuted (rule 21): within
// each 256B row-segment lane fetches chunk (lane&15)^(r&7) -> coalescing
// kept, swizzled LDS reads 2-way max (free, m136).
// Tile body: {issue A(t+2) x4 ; load B(t+1) x12 regs ; ds_read+cvt+48 MFMA ;
// vmcnt(16) ; barrier} — vmcnt FIFO: outstanding at the wait (old->young) =
// A(t+1)4, B(t)12, A(t+2)4, B(t+1)12, so vmcnt(16) retires exactly
// A(t+1)+B(t): each wave proves its OWN A(t+1) landed BEFORE the releasing
// barrier (wait-then-barrier, R8 lesson).
// B = wave-private fragment-major regs (R11-proven, compiler-counted).
// BM=128, BN=384 (x read once), grid 256, 8 waves 2M x 4N, acc[4][6].
// Outputs: Q,K bf16 [B*T][128]; V transposed bf16 [B][128][256].
// ---------------------------------------------------------------------------
__global__ __launch_bounds__(512, 2) void qkv_gemm(
    const float* __restrict__ x,
    const unsigned char* __restrict__ wt3,
    unsigned short* __restrict__ qo,
    unsigned short* __restrict__ ko,
    unsigned short* __restrict__ vto) {

    __shared__ char smem[131072];   // 4 x 32KB f32 A-tiles (source-swizzled)

    const int tid = threadIdx.x;
    const int bm  = blockIdx.x;               // 0..255 (M tiles of 128)
    const int lane = tid & 63, wid = tid >> 6;
    const int lm = lane & 15, l4 = lane >> 4;
    const int wm = wid >> 2, wn = wid & 3;    // 2 (M) x 4 (N)

    f32x4 acc[4][6];
#pragma unroll
    for (int i = 0; i < 4; ++i)
#pragma unroll
        for (int j = 0; j < 6; ++j) acc[i][j] = (f32x4)0.f;

    // ---- A staging geometry: 4 gload_lds per thread-wave issue ----
    // lane l, q: LDS row r = wid*16 + q*4 + (l>>4), chunk (l&15);
    // global src: x row (bm*128 + r), chunk (l&15)^(r&7)  [BUGFIX: +bm*128]
    const unsigned char* xb = (const unsigned char*)x;
    const unsigned char* asrc[4];
    int adst[4];
#pragma unroll
    for (int q = 0; q < 4; ++q) {
        int r = wid * 16 + q * 4 + (lane >> 4);
        asrc[q] = xb + (size_t)(bm * 128 + r) * 4096 +
                  ((size_t)((lane & 15) ^ (r & 7)) << 4);
        adst[q] = (wid * 4 + q) * 1024;       // wave-uniform
    }

    // ---- B fragment pointers (wave-private, fragment-major) ----
    const unsigned char* wbq[6];
#pragma unroll
    for (int ni = 0; ni < 6; ++ni)
        wbq[ni] = wt3 + (size_t)(wn * 6 + ni) * 32768 + (size_t)lane * 16;

    s16x8 af[4];
    s16x8 bX0[6], bX1[6], bY0[6], bY1[6];

#define ASTAGE(WB, T)                                                          \
    do {                                                                       \
        _Pragma("unroll")                                                      \
        for (int q = 0; q < 4; ++q)                                            \
            GLOAD_LDS16(asrc[q] + (T) * 256, smem + (WB) + adst[q]);           \
    } while (0)

#define BLOAD(D0, D1, T)                                                       \
    do {                                                                       \
        _Pragma("unroll")                                                      \
        for (int ni = 0; ni < 6; ++ni) {                                       \
            (D0)[ni] = *(const s16x8*)(wbq[ni] + (T) * 2048);                  \
            (D1)[ni] = *(const s16x8*)(wbq[ni] + (T) * 2048 + 1024);           \
        }                                                                      \
    } while (0)

#define AFREAD(RB, KKK)                                                        \
    do {                                                                       \
        _Pragma("unroll")                                                      \
        for (int mi = 0; mi < 4; ++mi) {                                       \
            int r_  = wm * 64 + mi * 16 + lm;                                  \
            int ci_ = (KKK) * 8 + l4 * 2;                                      \
            f32x4 lo_ = *(const f32x4*)(smem + (RB) + r_ * 256 +               \
                          (((ci_    ) ^ (r_ & 7)) << 4));                      \
            f32x4 hi_ = *(const f32x4*)(smem + (RB) + r_ * 256 +               \
                          (((ci_ + 1) ^ (r_ & 7)) << 4));                      \
            af[mi] = cvt8(lo_, hi_);                                           \
        }                                                                      \
    } while (0)

#define MFMA6(BQ)                                                              \
    do {                                                                       \
        __builtin_amdgcn_s_setprio(1);                                         \
        _Pragma("unroll")                                                      \
        for (int ni = 0; ni < 6; ++ni)                                         \
            _Pragma("unroll")                                                  \
            for (int mi = 0; mi < 4; ++mi)                                     \
                acc[mi][ni] = __builtin_amdgcn_mfma_f32_16x16x32_bf16(         \
                    af[mi], (BQ)[ni], acc[mi][ni], 0, 0, 0);                   \
        __builtin_amdgcn_s_setprio(0);                                         \
    } while (0)

#define WAITBAR(N)                                                             \
    do {                                                                       \
        asm volatile("s_waitcnt vmcnt(" #N ")" ::: "memory");                  \
        __builtin_amdgcn_s_barrier();                                          \
        asm volatile("" ::: "memory");                                         \
    } while (0)

    // ---- prologue: A(0)->buf0, A(1)->buf1, B(0)->bX; prove A(0) ----
    ASTAGE(0, 0);
    ASTAGE(32768, 1);
    BLOAD(bX0, bX1, 0);
    WAITBAR(16);                 // younger: A(1)x4 + B(0)x12

    for (int tp = 0; tp < 7; ++tp) {
        const int t   = tp * 2;
        const int rbE = (tp & 1) * 65536;            // buf for even tile
        const int wbE = ((tp + 1) & 1) * 65536;      // dest for A(t+2)
        // ===== even tile t =====
        ASTAGE(wbE, t + 2);
        BLOAD(bY0, bY1, t + 1);
        AFREAD(rbE, 0); MFMA6(bX0);
        AFREAD(rbE, 1); MFMA6(bX1);
        WAITBAR(16);             // proves A(t+1); A(t+2)4+B(t+1)12 in flight
        // ===== odd tile t+1 =====
        ASTAGE(wbE + 32768, t + 3);
        BLOAD(bX0, bX1, t + 2);
        AFREAD(rbE + 32768, 0); MFMA6(bY0);
        AFREAD(rbE + 32768, 1); MFMA6(bY1);
        WAITBAR(16);             // proves A(t+2)
    }
    // ===== tile 14 (buf2) =====
    BLOAD(bY0, bY1, 15);
    AFREAD(65536, 0); MFMA6(bX0);
    AFREAD(65536, 1); MFMA6(bX1);
    WAITBAR(12);                 // proves A(15); only B(15)x12 in flight
    // ===== tile 15 (buf3) =====
    AFREAD(98304, 0); MFMA6(bY0);
    AFREAD(98304, 1); MFMA6(bY1);

#undef ASTAGE
#undef BLOAD
#undef AFREAD
#undef MFMA6
#undef WAITBAR

    // ---- epilogue (verified R6) ----
#pragma unroll
    for (int mi = 0; mi < 4; ++mi) {
        int m0 = bm * 128 + wm * 64 + mi * 16 + l4 * 4;   // j adds 0..3
#pragma unroll
        for (int ni = 0; ni < 6; ++ni) {
            int nb  = wn * 96 + ni * 16;
            int mat = nb >> 7;                 // 0=Q 1=K 2=V
            int col = (nb & 127) + lm;
            if (mat == 2) {
                int bb2 = m0 >> 8, tt = m0 & 255;
                s16x4 w4;
#pragma unroll
                for (int j = 0; j < 4; ++j) w4[j] = (short)f2bf(acc[mi][ni][j]);
                *(s16x4*)(vto + ((size_t)bb2 * 128 + col) * 256 + tt) = w4;
            } else {
                unsigned short* dst = (mat == 0) ? qo : ko;
#pragma unroll
                for (int j = 0; j < 4; ++j)
                    dst[(size_t)(m0 + j) * 128 + col] = f2bf(acc[mi][ni][j]);
            }
        }
    }
}

// ---------------------------------------------------------------------------
// Kernel 2: causal attention (unchanged, verified; ~7µs).
// ---------------------------------------------------------------------------
__global__ __launch_bounds__(512) void attn(
    const unsigned short* __restrict__ q,
    const unsigned short* __restrict__ k,
    const unsigned short* __restrict__ vt,
    float* __restrict__ out) {

    __shared__ char pbuf[65536];               // 8 waves x [16][256] bf16

    const int tid = threadIdx.x, wid = tid >> 6, lane = tid & 63;
    const int lm = lane & 15, l4 = lane >> 4;
    const int b = blockIdx.x >> 1, qt = blockIdx.x & 1;
    const int qbase = qt << 7;
    const int t0 = qbase + wid * 16;
    const int nfrags = (qbase + 128) >> 4;
    const int nkf    = (qbase + 128) >> 5;

    const unsigned short* qrow = q + (size_t)(b * 256 + t0 + lm) * 128 + l4 * 8;
    s16x8 qf[4];
#pragma unroll
    for (int kf = 0; kf < 4; ++kf) qf[kf] = *(const s16x8*)(qrow + kf * 32);

    f32x4 sacc[16];
#pragma unroll
    for (int i = 0; i < 16; ++i) sacc[i] = (f32x4)0.f;

    const unsigned short* kbase = k + (size_t)(b * 256) * 128 + l4 * 8;
#pragma unroll
    for (int nf = 0; nf < 16; ++nf) {
        if (nf < nfrags) {
#pragma unroll
            for (int kf = 0; kf < 4; ++kf) {
                s16x8 a = *(const s16x8*)(kbase + (size_t)(nf * 16 + lm) * 128 + kf * 32);
                sacc[nf] = __builtin_amdgcn_mfma_f32_16x16x32_bf16(a, qf[kf], sacc[nf], 0, 0, 0);
            }
        }
    }

    const float scale = 0.08838834764831845f;  // 1/sqrt(128)
    const int tg = t0 + lm;
    float mx = -1e30f;
#pragma unroll
    for (int nf = 0; nf < 16; ++nf) {
        if (nf < nfrags) {
#pragma unroll
            for (int j = 0; j < 4; ++j) {
                int kv = nf * 16 + l4 * 4 + j;
                float s = sacc[nf][j] * scale;
                s = (kv > tg) ? -1e30f : s;
                sacc[nf][j] = s;
                mx = fmaxf(mx, s);
            }
        }
    }
    mx = fmaxf(mx, __shfl_xor(mx, 16));
    mx = fmaxf(mx, __shfl_xor(mx, 32));
    float sum = 0.f;
#pragma unroll
    for (int nf = 0; nf < 16; ++nf) {
        if (nf < nfrags) {
#pragma unroll
            for (int j = 0; j < 4; ++j) {
                float p = __expf(sacc[nf][j] - mx);
                sacc[nf][j] = p;
                sum += p;
            }
        }
    }
    sum += __shfl_xor(sum, 16);
    sum += __shfl_xor(sum, 32);
    float rinv = 1.0f / sum;

    char* pw = pbuf + wid * 8192 + lm * 512;
#pragma unroll
    for (int nf = 0; nf < 16; ++nf) {
        if (nf < nfrags) {
            s16x4 w;
#pragma unroll
            for (int j = 0; j < 4; ++j) w[j] = (short)f2bf(sacc[nf][j] * rinv);
            *(s16x4*)(pw + ((nf * 32 + l4 * 8) ^ ((lm & 7) << 4))) = w;
        }
    }
    asm volatile("s_waitcnt lgkmcnt(0)" ::: "memory");

    f32x4 oacc[8];
#pragma unroll
    for (int i = 0; i < 8; ++i) oacc[i] = (f32x4)0.f;

    const unsigned short* vbase = vt + (size_t)b * 32768 + l4 * 8;
#pragma unroll
    for (int kvf = 0; kvf < 8; ++kvf) {
        if (kvf < nkf) {
            s16x8 pf = *(const s16x8*)(pbuf + wid * 8192 + lm * 512 +
                        ((kvf * 64 + l4 * 16) ^ ((lm & 7) << 4)));
#pragma unroll
            for (int hf = 0; hf < 8; ++hf) {
                s16x8 a = *(const s16x8*)(vbase + (size_t)(hf * 16 + lm) * 256 + kvf * 32);
                oacc[hf] = __builtin_amdgcn_mfma_f32_16x16x32_bf16(a, pf, oacc[hf], 0, 0, 0);
            }
        }
    }

    float* ob = out + (size_t)(b * 256 + t0 + lm) * 128 + l4 * 4;
#pragma unroll
    for (int hf = 0; hf < 8; ++hf)
        *(f32x4*)(ob + hf * 16) = oacc[hf];
}

// ---------------------------------------------------------------------------
extern "C" void kernel_launch(void* const* d_in, const int* in_sizes, int n_in,
                              void* d_out, int out_size, void* d_ws, size_t ws_size,
                              hipStream_t stream) {
    const float* x  = (const float*)d_in[0];
    const float* Wq = (const float*)d_in[1];
    const float* Wk = (const float*)d_in[2];
    const float* Wv = (const float*)d_in[3];
    float* out = (float*)d_out;

    char* ws = (char*)d_ws;
    unsigned char*  wt = (unsigned char*)(ws);                     // 786432 B (fragment-major)
    unsigned short* qb = (unsigned short*)(ws + 786432);
    unsigned short* kb = (unsigned short*)(ws + 786432 + 8388608);
    unsigned short* vb = (unsigned short*)(ws + 786432 + 2 * 8388608);

    prep_wt<<<384, 256, 0, stream>>>(Wq, Wk, Wv, wt);
    qkv_gemm<<<256, 512, 0, stream>>>(x, wt, qb, kb, vb);
    attn<<<256, 512, 0, stream>>>(qb, kb, vb, out);
}

// Round 16
// 79.178 us; speedup vs baseline: 1.2504x; 1.1156x over previous
//
#include <hip/hip_runtime.h>

typedef float  f32x4  __attribute__((ext_vector_type(4)));
typedef short  s16x8  __attribute__((ext_vector_type(8)));
typedef short  s16x4  __attribute__((ext_vector_type(4)));

__device__ __forceinline__ unsigned short f2bf(float f) {
    unsigned int u = __float_as_uint(f);
    return (unsigned short)((u + 0x7FFFu + ((u >> 16) & 1u)) >> 16);
}

__device__ __forceinline__ s16x8 cvt8(f32x4 a, f32x4 b) {
    union { unsigned int u[4]; s16x8 v; } r;
    asm("v_cvt_pk_bf16_f32 %0, %1, %2" : "=v"(r.u[0]) : "v"(a[0]), "v"(a[1]));
    asm("v_cvt_pk_bf16_f32 %0, %1, %2" : "=v"(r.u[1]) : "v"(a[2]), "v"(a[3]));
    asm("v_cvt_pk_bf16_f32 %0, %1, %2" : "=v"(r.u[2]) : "v"(b[0]), "v"(b[1]));
    asm("v_cvt_pk_bf16_f32 %0, %1, %2" : "=v"(r.u[3]) : "v"(b[2]), "v"(b[3]));
    return r.v;
}

#define GLOAD_LDS16(g, l) __builtin_amdgcn_global_load_lds(                    \
    (const __attribute__((address_space(1))) void*)(g),                        \
    (__attribute__((address_space(3))) void*)(l), 16, 0, 0)

// ---------------------------------------------------------------------------
// Kernel 0: wt2 = swizzle-tiled bf16 weights (R6/R7-verified, 0 conflicts):
// 16 K-tiles of [384][128B], row-XOR-swizzled so a linear global_load_lds
// reproduces the conflict-free swizzled LDS layout (rule 21).
// ---------------------------------------------------------------------------
__global__ void prep_wt(const float* __restrict__ Wq,
                        const float* __restrict__ Wk,
                        const float* __restrict__ Wv,
                        unsigned char* __restrict__ wt2) {
    int n = blockIdx.x;                       // 0..383
    const float* W = (n < 128) ? Wq : ((n < 256) ? Wk : Wv);
    int h = n & 127;
    for (int k = threadIdx.x; k < 1024; k += blockDim.x) {
        unsigned short v = f2bf(W[(size_t)k * 128 + h]);
        size_t off = (size_t)(k >> 6) * 49152 + (size_t)n * 128 +
                     (((k & 63) * 2) ^ ((n & 7) << 4));
        *(unsigned short*)(wt2 + off) = v;
    }
}

// ---------------------------------------------------------------------------
// Kernel 1: QKV GEMM — the {355 MB, 4 waves/SIMD} quadrant.
// Flat-rate model (fits R2/R5/R9/R12/R15 + fill kernels): time = bytes/7.3TB/s
// with a latency residual when TLP < ~4 waves/SIMD.  This config minimizes
// BOTH: BM=128, BN=384, grid 256 -> A 134MB + B 196MB (48KB/CU/tile via
// SHARED LDS, no duplication) + stores 25MB = 355MB; and 16 waves of 64
// threads... (1024 thr) with wave tile 64x48 (acc[4][3]=48) keeps VGPR ~104
// <= 128 -> launch_bounds(1024,4) = 4 waves/SIMD.
// B staged by global_load_lds from pre-swizzled wt2 (3x1KB chunks per wave);
// A reg-staged f32->bf16 (R2-verified swizzle).  ONE barrier per tile,
// wait-then-barrier: per-tile issue order B(t+1)x3 then A(t+2)x2, so
// vmcnt(2) before the barrier proves this wave's B(t+1) landed while A(t+2)
// stays in flight (R8 lesson).  vmcnt drains only at tile 14.
// Outputs: Q,K bf16 [B*T][128]; V transposed bf16 [B][128][256].
// ---------------------------------------------------------------------------
__global__ __launch_bounds__(1024, 4) void qkv_gemm(
    const float* __restrict__ x,
    const unsigned char* __restrict__ wt2,
    unsigned short* __restrict__ qo,
    unsigned short* __restrict__ ko,
    unsigned short* __restrict__ vto) {

    __shared__ char smem[131072];   // A: 2x16K @0,16384 ; B: 2x48K @32768,81920

    const int tid = threadIdx.x;
    const int bm  = blockIdx.x;               // 0..255 (M tiles of 128)
    const int lane = tid & 63, wid = tid >> 6; // wid 0..15
    const int lm = lane & 15, l4 = lane >> 4;
    const int wm = wid >> 3, wn = wid & 7;    // 2 (M) x 8 (N) waves

    f32x4 acc[4][3];
#pragma unroll
    for (int i = 0; i < 4; ++i)
#pragma unroll
        for (int j = 0; j < 3; ++j) acc[i][j] = (f32x4)0.f;

    // ---- A staging: thread -> row tid>>3, 8 consecutive f32 ----
    const int ar  = tid >> 3;                 // 0..127
    const int ac8 = tid & 7;
    const float* xp = x + (size_t)(bm * 128 + ar) * 1024 + ac8 * 8;
    const int aw = ar * 128 + ((ac8 * 16) ^ ((ar & 7) << 4));

    // ---- B staging: wave wid owns chunks wid*3 .. +2 (1KB each) ----
    const int ci0 = wid * 3;
    const unsigned char* bsrc = wt2 + (size_t)ci0 * 1024 + (size_t)lane * 16;

    // ---- fragment rows ----
    int amr[4], bnr[3];
#pragma unroll
    for (int mi = 0; mi < 4; ++mi) amr[mi] = wm * 64 + mi * 16 + lm;
#pragma unroll
    for (int ni = 0; ni < 3; ++ni) bnr[ni] = wn * 48 + ni * 16 + lm;

    f32x4 pa0, pa1;

    // ---- prologue: B(0) gloads -> buf0, A(0) publish, pa = A(1) ----
    {
        f32x4 a0 = *(const f32x4*)(xp);
        f32x4 a1 = *(const f32x4*)(xp + 4);
#pragma unroll
        for (int c = 0; c < 3; ++c)
            GLOAD_LDS16(bsrc + c * 1024, smem + 32768 + (ci0 + c) * 1024);
        *(s16x8*)(smem + aw) = cvt8(a0, a1);
        pa0 = *(const f32x4*)(xp + 64);
        pa1 = *(const f32x4*)(xp + 68);
        asm volatile("s_waitcnt vmcnt(2)" ::: "memory");  // B(0) landed
        asm volatile("s_waitcnt lgkmcnt(0)" ::: "memory");
        __builtin_amdgcn_s_barrier();
    }

    for (int t = 0; t < 16; ++t) {
        const int p   = t & 1;
        const int ab  = p * 16384,       bb  = 32768 + p * 49152;
        const int ab2 = (p ^ 1) * 16384, bb2 = 32768 + (p ^ 1) * 49152;
        // ---- issue B(t+1) gloads into other buffer (oldest this tile) ----
        if (t < 15) {
            const unsigned char* ws = bsrc + (size_t)(t + 1) * 49152;
#pragma unroll
            for (int c = 0; c < 3; ++c)
                GLOAD_LDS16(ws + c * 1024, smem + bb2 + (ci0 + c) * 1024);
        }
        // ---- MFMA: 2 x (7 ds_read + 12 MFMA) from buf p ----
#pragma unroll
        for (int kkk = 0; kkk < 2; ++kkk) {
            s16x8 af[4], bf[3];
#pragma unroll
            for (int mi = 0; mi < 4; ++mi)
                af[mi] = *(const s16x8*)(smem + ab + amr[mi] * 128 +
                           ((kkk * 64 + l4 * 16) ^ ((amr[mi] & 7) << 4)));
#pragma unroll
            for (int ni = 0; ni < 3; ++ni)
                bf[ni] = *(const s16x8*)(smem + bb + bnr[ni] * 128 +
                           ((kkk * 64 + l4 * 16) ^ ((bnr[ni] & 7) << 4)));
            __builtin_amdgcn_s_setprio(1);
#pragma unroll
            for (int ni = 0; ni < 3; ++ni)
#pragma unroll
                for (int mi = 0; mi < 4; ++mi)
                    acc[mi][ni] = __builtin_amdgcn_mfma_f32_16x16x32_bf16(
                        af[mi], bf[ni], acc[mi][ni], 0, 0, 0);
            __builtin_amdgcn_s_setprio(0);
        }
        // ---- stage A(t+1) (compiler waits pa loads only: vmcnt(3)) ----
        if (t < 15) {
            *(s16x8*)(smem + ab2 + aw) = cvt8(pa0, pa1);
            if (t < 14) {
                const float* xq = xp + (t + 2) * 64;
                pa0 = *(const f32x4*)(xq);
                pa1 = *(const f32x4*)(xq + 4);
                // prove B(t+1): outstanding = [B(t+1)x3, A(t+2)x2]
                asm volatile("s_waitcnt vmcnt(2)" ::: "memory");
            } else {
                asm volatile("s_waitcnt vmcnt(0)" ::: "memory");  // B(15)
            }
            asm volatile("s_waitcnt lgkmcnt(0)" ::: "memory");
            __builtin_amdgcn_s_barrier();
        }
    }

    // ---- epilogue (layout verified R12) ----
#pragma unroll
    for (int mi = 0; mi < 4; ++mi) {
        int m0 = bm * 128 + wm * 64 + mi * 16 + l4 * 4;  // j adds 0..3
#pragma unroll
        for (int ni = 0; ni < 3; ++ni) {
            int nb  = wn * 48 + ni * 16;
            int mat = nb >> 7;                 // 0=Q 1=K 2=V
            int col = (nb & 127) + lm;
            if (mat == 2) {
                int bb2_ = m0 >> 8, tt = m0 & 255;
                s16x4 w4;
#pragma unroll
                for (int j = 0; j < 4; ++j) w4[j] = (short)f2bf(acc[mi][ni][j]);
                *(s16x4*)(vto + ((size_t)bb2_ * 128 + col) * 256 + tt) = w4;
            } else {
                unsigned short* dst = (mat == 0) ? qo : ko;
#pragma unroll
                for (int j = 0; j < 4; ++j)
                    dst[(size_t)(m0 + j) * 128 + col] = f2bf(acc[mi][ni][j]);
            }
        }
    }
}

// ---------------------------------------------------------------------------
// Kernel 2: causal attention (unchanged, verified; ~7µs).
// ---------------------------------------------------------------------------
__global__ __launch_bounds__(512) void attn(
    const unsigned short* __restrict__ q,
    const unsigned short* __restrict__ k,
    const unsigned short* __restrict__ vt,
    float* __restrict__ out) {

    __shared__ char pbuf[65536];               // 8 waves x [16][256] bf16

    const int tid = threadIdx.x, wid = tid >> 6, lane = tid & 63;
    const int lm = lane & 15, l4 = lane >> 4;
    const int b = blockIdx.x >> 1, qt = blockIdx.x & 1;
    const int qbase = qt << 7;
    const int t0 = qbase + wid * 16;
    const int nfrags = (qbase + 128) >> 4;
    const int nkf    = (qbase + 128) >> 5;

    const unsigned short* qrow = q + (size_t)(b * 256 + t0 + lm) * 128 + l4 * 8;
    s16x8 qf[4];
#pragma unroll
    for (int kf = 0; kf < 4; ++kf) qf[kf] = *(const s16x8*)(qrow + kf * 32);

    f32x4 sacc[16];
#pragma unroll
    for (int i = 0; i < 16; ++i) sacc[i] = (f32x4)0.f;

    const unsigned short* kbase = k + (size_t)(b * 256) * 128 + l4 * 8;
#pragma unroll
    for (int nf = 0; nf < 16; ++nf) {
        if (nf < nfrags) {
#pragma unroll
            for (int kf = 0; kf < 4; ++kf) {
                s16x8 a = *(const s16x8*)(kbase + (size_t)(nf * 16 + lm) * 128 + kf * 32);
                sacc[nf] = __builtin_amdgcn_mfma_f32_16x16x32_bf16(a, qf[kf], sacc[nf], 0, 0, 0);
            }
        }
    }

    const float scale = 0.08838834764831845f;  // 1/sqrt(128)
    const int tg = t0 + lm;
    float mx = -1e30f;
#pragma unroll
    for (int nf = 0; nf < 16; ++nf) {
        if (nf < nfrags) {
#pragma unroll
            for (int j = 0; j < 4; ++j) {
                int kv = nf * 16 + l4 * 4 + j;
                float s = sacc[nf][j] * scale;
                s = (kv > tg) ? -1e30f : s;
                sacc[nf][j] = s;
                mx = fmaxf(mx, s);
            }
        }
    }
    mx = fmaxf(mx, __shfl_xor(mx, 16));
    mx = fmaxf(mx, __shfl_xor(mx, 32));
    float sum = 0.f;
#pragma unroll
    for (int nf = 0; nf < 16; ++nf) {
        if (nf < nfrags) {
#pragma unroll
            for (int j = 0; j < 4; ++j) {
                float p = __expf(sacc[nf][j] - mx);
                sacc[nf][j] = p;
                sum += p;
            }
        }
    }
    sum += __shfl_xor(sum, 16);
    sum += __shfl_xor(sum, 32);
    float rinv = 1.0f / sum;

    char* pw = pbuf + wid * 8192 + lm * 512;
#pragma unroll
    for (int nf = 0; nf < 16; ++nf) {
        if (nf < nfrags) {
            s16x4 w;
#pragma unroll
            for (int j = 0; j < 4; ++j) w[j] = (short)f2bf(sacc[nf][j] * rinv);
            *(s16x4*)(pw + ((nf * 32 + l4 * 8) ^ ((lm & 7) << 4))) = w;
        }
    }
    asm volatile("s_waitcnt lgkmcnt(0)" ::: "memory");

    f32x4 oacc[8];
#pragma unroll
    for (int i = 0; i < 8; ++i) oacc[i] = (f32x4)0.f;

    const unsigned short* vbase = vt + (size_t)b * 32768 + l4 * 8;
#pragma unroll
    for (int kvf = 0; kvf < 8; ++kvf) {
        if (kvf < nkf) {
            s16x8 pf = *(const s16x8*)(pbuf + wid * 8192 + lm * 512 +
                        ((kvf * 64 + l4 * 16) ^ ((lm & 7) << 4)));
#pragma unroll
            for (int hf = 0; hf < 8; ++hf) {
                s16x8 a = *(const s16x8*)(vbase + (size_t)(hf * 16 + lm) * 256 + kvf * 32);
                oacc[hf] = __builtin_amdgcn_mfma_f32_16x16x32_bf16(a, pf, oacc[hf], 0, 0, 0);
            }
        }
    }

    float* ob = out + (size_t)(b * 256 + t0 + lm) * 128 + l4 * 4;
#pragma unroll
    for (int hf = 0; hf < 8; ++hf)
        *(f32x4*)(ob + hf * 16) = oacc[hf];
}

// ---------------------------------------------------------------------------
extern "C" void kernel_launch(void* const* d_in, const int* in_sizes, int n_in,
                              void* d_out, int out_size, void* d_ws, size_t ws_size,
                              hipStream_t stream) {
    const float* x  = (const float*)d_in[0];
    const float* Wq = (const float*)d_in[1];
    const float* Wk = (const float*)d_in[2];
    const float* Wv = (const float*)d_in[3];
    float* out = (float*)d_out;

    char* ws = (char*)d_ws;
    unsigned char*  wt = (unsigned char*)(ws);                     // 786432 B (swizzle-tiled)
    unsigned short* qb = (unsigned short*)(ws + 786432);
    unsigned short* kb = (unsigned short*)(ws + 786432 + 8388608);
    unsigned short* vb = (unsigned short*)(ws + 786432 + 2 * 8388608);

    prep_wt<<<384, 256, 0, stream>>>(Wq, Wk, Wv, wt);
    qkv_gemm<<<256, 1024, 0, stream>>>(x, wt, qb, kb, vb);
    attn<<<256, 512, 0, stream>>>(qb, kb, vb, out);
}

// Round 17
// 78.554 us; speedup vs baseline: 1.2603x; 1.0079x over previous
//
#include <hip/hip_runtime.h>

typedef float  f32x4  __attribute__((ext_vector_type(4)));
typedef short  s16x8  __attribute__((ext_vector_type(8)));
typedef short  s16x4  __attribute__((ext_vector_type(4)));

__device__ __forceinline__ unsigned short f2bf(float f) {
    unsigned int u = __float_as_uint(f);
    return (unsigned short)((u + 0x7FFFu + ((u >> 16) & 1u)) >> 16);
}

__device__ __forceinline__ s16x4 cvt4(f32x4 v) {
    union { unsigned int u[2]; s16x4 h; } r;
    asm("v_cvt_pk_bf16_f32 %0, %1, %2" : "=v"(r.u[0]) : "v"(v[0]), "v"(v[1]));
    asm("v_cvt_pk_bf16_f32 %0, %1, %2" : "=v"(r.u[1]) : "v"(v[2]), "v"(v[3]));
    return r.h;
}

// ---------------------------------------------------------------------------
// Kernel 0: wt3 = FRAGMENT-MAJOR bf16 weights (verified R9/R11/R12).
// Fragment (n16,ks,kkk) = one wave's exact MFMA B-operand (64 lanes x 16B):
// value = W_sel[k][n&127], n = n16*16 + (lane&15),
// k = ks*64 + kkk*32 + (lane>>4)*8 + j; byte = fragid*1024 + lane*16 + j*2.
// ---------------------------------------------------------------------------
__global__ void prep_wt(const float* __restrict__ Wq,
                        const float* __restrict__ Wk,
                        const float* __restrict__ Wv,
                        unsigned char* __restrict__ wt3) {
    int n = blockIdx.x;                       // 0..383
    const float* W = (n < 128) ? Wq : ((n < 256) ? Wk : Wv);
    int h = n & 127;
    int n16 = n >> 4, lmn = n & 15;
    for (int k = threadIdx.x; k < 1024; k += blockDim.x) {
        unsigned short v = f2bf(W[(size_t)k * 128 + h]);
        int ks = k >> 6, rem = k & 63;
        int kkk = rem >> 5, l4_ = (rem >> 3) & 3, j = rem & 7;
        int lane = l4_ * 16 + lmn;
        size_t off = (size_t)(n16 * 32 + ks * 2 + kkk) * 1024 + lane * 16 + j * 2;
        *(unsigned short*)(wt3 + off) = v;
    }
}

// ---------------------------------------------------------------------------
// Kernel 1: QKV GEMM — PRODUCER-CONSUMER WAVE SPECIALIZATION, zero barriers
// after init.  Diagnosis: 13 lockstep variants all pin at ~11K cy/tile with
// every pipe idle — the shared invariant is waves alternating mem-burst /
// compute-burst in a block-wide cadence.  Here: waves 6,7 = A-producers
// (pure streaming like the 7.2TB/s fill kernel: 16 back-to-back f32x4 loads
// per tile -> cvt_pk -> swizzled ds_write into a 4-slot ring -> set flag);
// waves 0-5 = consumers (poll flag -> 16 ds_read + 64 MFMA + 8 B-reg loads
// per tile -> done flag).  Sync = LDS flags + s_sleep polling (LDS is
// per-CU coherent; producer does lgkmcnt(0) before flag-set, so a consumer
// observing the flag sees the data).  Poll loops have overflow guards.
// BM=128, BN=384 (x read once), grid 256 = 1 block/CU.  Consumer c owns
// cols c*64..+63 (acc[8][4]); B wave-private regs from fragment-major wt3.
// Outputs: Q,K bf16 [B*T][128]; V transposed bf16 [B][128][256].
// ---------------------------------------------------------------------------
__global__ __launch_bounds__(512, 2) void qkv_gemm(
    const float* __restrict__ x,
    const unsigned char* __restrict__ wt3,
    unsigned short* __restrict__ qo,
    unsigned short* __restrict__ ko,
    unsigned short* __restrict__ vto) {

    __shared__ char aring[65536];             // 4 slots x 16KB bf16 A-tiles
    __shared__ int  sflag[2][4];              // producer p filled slot s (tile+1)
    __shared__ int  sdone[6][4];              // consumer c done slot s (tile+1)

    const int tid = threadIdx.x;
    const int bm  = blockIdx.x;               // 0..255 (M tiles of 128)
    const int lane = tid & 63, wid = tid >> 6;
    const int lm = lane & 15, l4 = lane >> 4;

    if (tid < 8)  ((int*)sflag)[tid] = 0;
    if (tid < 24) ((int*)sdone)[tid] = 0;
    __syncthreads();                          // the only block-wide barrier

#define POLL(PTR, VAL)                                                         \
    do {                                                                       \
        volatile int* _p = (PTR);                                              \
        int _g = 0;                                                            \
        while (*_p < (VAL) && _g < (1 << 22)) {                                \
            __builtin_amdgcn_s_sleep(1); ++_g;                                 \
        }                                                                      \
    } while (0)

    if (wid >= 6) {
        // ================= PRODUCER p (streams A) =================
        const int p = wid - 6;
        const int lrow = p * 64 + (lane >> 4);            // + i*4
        const float* xsrc = x + (size_t)(bm * 128 + lrow) * 1024 + (lane & 15) * 4;
        for (int t = 0; t < 16; ++t) {
            const int s = t & 3;
            if (t >= 4) {
#pragma unroll
                for (int c = 0; c < 6; ++c) POLL(&sdone[c][s], t - 3);
            }
            f32x4 v[16];
#pragma unroll
            for (int i = 0; i < 16; ++i)                   // 16 KB burst, max MLP
                v[i] = *(const f32x4*)(xsrc + i * 4096 + t * 64);
#pragma unroll
            for (int i = 0; i < 16; ++i) {
                int row = lrow + i * 4;
                *(s16x4*)(aring + s * 16384 + row * 128 +
                          (((lane & 15) * 8) ^ ((row & 7) << 4))) = cvt4(v[i]);
            }
            asm volatile("s_waitcnt lgkmcnt(0)" ::: "memory");
            sflag[p][s] = t + 1;               // publish
        }
        return;                                // producers exit; no barriers left
    }

    // ================= CONSUMER c (pure compute) =================
    const int c = wid;                         // 0..5 ; cols c*64..c*64+63
    f32x4 acc[8][4];
#pragma unroll
    for (int i = 0; i < 8; ++i)
#pragma unroll
        for (int j = 0; j < 4; ++j) acc[i][j] = (f32x4)0.f;

    const unsigned char* wbq[4];
#pragma unroll
    for (int ni = 0; ni < 4; ++ni)
        wbq[ni] = wt3 + (size_t)(c * 4 + ni) * 32768 + (size_t)lane * 16;

    s16x8 bqA[4], bqB[4];
#pragma unroll
    for (int ni = 0; ni < 4; ++ni) bqA[ni] = *(const s16x8*)(wbq[ni]);  // B(0,k0)

#define HALF(BQ, KOFF, TB)                                                     \
    do {                                                                       \
        _Pragma("unroll")                                                      \
        for (int mp = 0; mp < 4; ++mp) {                                       \
            int r0 = mp * 32 + lm, r1 = mp * 32 + 16 + lm;                     \
            s16x8 a0 = *(const s16x8*)(aring + (TB) + r0 * 128 +               \
                        (((KOFF) + l4 * 16) ^ ((r0 & 7) << 4)));               \
            s16x8 a1 = *(const s16x8*)(aring + (TB) + r1 * 128 +               \
                        (((KOFF) + l4 * 16) ^ ((r1 & 7) << 4)));               \
            _Pragma("unroll")                                                  \
            for (int ni = 0; ni < 4; ++ni) {                                   \
                acc[mp * 2][ni] = __builtin_amdgcn_mfma_f32_16x16x32_bf16(     \
                    a0, (BQ)[ni], acc[mp * 2][ni], 0, 0, 0);                   \
                acc[mp * 2 + 1][ni] = __builtin_amdgcn_mfma_f32_16x16x32_bf16( \
                    a1, (BQ)[ni], acc[mp * 2 + 1][ni], 0, 0, 0);               \
            }                                                                  \
        }                                                                      \
    } while (0)

    for (int t = 0; t < 16; ++t) {
        const int s = t & 3;
        const int tb = s * 16384;
        POLL(&sflag[0][s], t + 1);
        POLL(&sflag[1][s], t + 1);
        // kkk0: issue B(t,kkk1); compute with bqA
#pragma unroll
        for (int ni = 0; ni < 4; ++ni)
            bqB[ni] = *(const s16x8*)(wbq[ni] + t * 2048 + 1024);
        HALF(bqA, 0, tb);
        // kkk1: issue B(t+1,kkk0); compute with bqB
        if (t < 15) {
#pragma unroll
            for (int ni = 0; ni < 4; ++ni)
                bqA[ni] = *(const s16x8*)(wbq[ni] + (t + 1) * 2048);
        }
        HALF(bqB, 64, tb);
        asm volatile("s_waitcnt lgkmcnt(0)" ::: "memory");  // slot reads retired
        sdone[c][s] = t + 1;                                // release slot
    }

#undef HALF
#undef POLL

    // ---- epilogue: consumer c covers one matrix half ----
    const int mat = c >> 1;                    // 0=Q 1=K 2=V
    const int cb  = (c & 1) * 64;
#pragma unroll
    for (int mi = 0; mi < 8; ++mi) {
        int m0 = bm * 128 + mi * 16 + l4 * 4;  // global row (j adds 0..3)
#pragma unroll
        for (int ni = 0; ni < 4; ++ni) {
            int col = cb + ni * 16 + lm;
            if (mat == 2) {
                int bb = m0 >> 8, tt = m0 & 255;
                s16x4 w4;
#pragma unroll
                for (int j = 0; j < 4; ++j) w4[j] = (short)f2bf(acc[mi][ni][j]);
                *(s16x4*)(vto + ((size_t)bb * 128 + col) * 256 + tt) = w4;
            } else {
                unsigned short* dst = (mat == 0) ? qo : ko;
#pragma unroll
                for (int j = 0; j < 4; ++j)
                    dst[(size_t)(m0 + j) * 128 + col] = f2bf(acc[mi][ni][j]);
            }
        }
    }
}

// ---------------------------------------------------------------------------
// Kernel 2: causal attention (unchanged, verified; ~7µs).
// ---------------------------------------------------------------------------
__global__ __launch_bounds__(512) void attn(
    const unsigned short* __restrict__ q,
    const unsigned short* __restrict__ k,
    const unsigned short* __restrict__ vt,
    float* __restrict__ out) {

    __shared__ char pbuf[65536];               // 8 waves x [16][256] bf16

    const int tid = threadIdx.x, wid = tid >> 6, lane = tid & 63;
    const int lm = lane & 15, l4 = lane >> 4;
    const int b = blockIdx.x >> 1, qt = blockIdx.x & 1;
    const int qbase = qt << 7;
    const int t0 = qbase + wid * 16;
    const int nfrags = (qbase + 128) >> 4;
    const int nkf    = (qbase + 128) >> 5;

    const unsigned short* qrow = q + (size_t)(b * 256 + t0 + lm) * 128 + l4 * 8;
    s16x8 qf[4];
#pragma unroll
    for (int kf = 0; kf < 4; ++kf) qf[kf] = *(const s16x8*)(qrow + kf * 32);

    f32x4 sacc[16];
#pragma unroll
    for (int i = 0; i < 16; ++i) sacc[i] = (f32x4)0.f;

    const unsigned short* kbase = k + (size_t)(b * 256) * 128 + l4 * 8;
#pragma unroll
    for (int nf = 0; nf < 16; ++nf) {
        if (nf < nfrags) {
#pragma unroll
            for (int kf = 0; kf < 4; ++kf) {
                s16x8 a = *(const s16x8*)(kbase + (size_t)(nf * 16 + lm) * 128 + kf * 32);
                sacc[nf] = __builtin_amdgcn_mfma_f32_16x16x32_bf16(a, qf[kf], sacc[nf], 0, 0, 0);
            }
        }
    }

    const float scale = 0.08838834764831845f;  // 1/sqrt(128)
    const int tg = t0 + lm;
    float mx = -1e30f;
#pragma unroll
    for (int nf = 0; nf < 16; ++nf) {
        if (nf < nfrags) {
#pragma unroll
            for (int j = 0; j < 4; ++j) {
                int kv = nf * 16 + l4 * 4 + j;
                float s = sacc[nf][j] * scale;
                s = (kv > tg) ? -1e30f : s;
                sacc[nf][j] = s;
                mx = fmaxf(mx, s);
            }
        }
    }
    mx = fmaxf(mx, __shfl_xor(mx, 16));
    mx = fmaxf(mx, __shfl_xor(mx, 32));
    float sum = 0.f;
#pragma unroll
    for (int nf = 0; nf < 16; ++nf) {
        if (nf < nfrags) {
#pragma unroll
            for (int j = 0; j < 4; ++j) {
                float p = __expf(sacc[nf][j] - mx);
                sacc[nf][j] = p;
                sum += p;
            }
        }
    }
    sum += __shfl_xor(sum, 16);
    sum += __shfl_xor(sum, 32);
    float rinv = 1.0f / sum;

    char* pw = pbuf + wid * 8192 + lm * 512;
#pragma unroll
    for (int nf = 0; nf < 16; ++nf) {
        if (nf < nfrags) {
            s16x4 w;
#pragma unroll
            for (int j = 0; j < 4; ++j) w[j] = (short)f2bf(sacc[nf][j] * rinv);
            *(s16x4*)(pw + ((nf * 32 + l4 * 8) ^ ((lm & 7) << 4))) = w;
        }
    }
    asm volatile("s_waitcnt lgkmcnt(0)" ::: "memory");

    f32x4 oacc[8];
#pragma unroll
    for (int i = 0; i < 8; ++i) oacc[i] = (f32x4)0.f;

    const unsigned short* vbase = vt + (size_t)b * 32768 + l4 * 8;
#pragma unroll
    for (int kvf = 0; kvf < 8; ++kvf) {
        if (kvf < nkf) {
            s16x8 pf = *(const s16x8*)(pbuf + wid * 8192 + lm * 512 +
                        ((kvf * 64 + l4 * 16) ^ ((lm & 7) << 4)));
#pragma unroll
            for (int hf = 0; hf < 8; ++hf) {
                s16x8 a = *(const s16x8*)(vbase + (size_t)(hf * 16 + lm) * 256 + kvf * 32);
                oacc[hf] = __builtin_amdgcn_mfma_f32_16x16x32_bf16(a, pf, oacc[hf], 0, 0, 0);
            }
        }
    }

    float* ob = out + (size_t)(b * 256 + t0 + lm) * 128 + l4 * 4;
#pragma unroll
    for (int hf = 0; hf < 8; ++hf)
        *(f32x4*)(ob + hf * 16) = oacc[hf];
}

// ---------------------------------------------------------------------------
extern "C" void kernel_launch(void* const* d_in, const int* in_sizes, int n_in,
                              void* d_out, int out_size, void* d_ws, size_t ws_size,
                              hipStream_t stream) {
    const float* x  = (const float*)d_in[0];
    const float* Wq = (const float*)d_in[1];
    const float* Wk = (const float*)d_in[2];
    const float* Wv = (const float*)d_in[3];
    float* out = (float*)d_out;

    char* ws = (char*)d_ws;
    unsigned char*  wt = (unsigned char*)(ws);                     // 786432 B (fragment-major)
    unsigned short* qb = (unsigned short*)(ws + 786432);
    unsigned short* kb = (unsigned short*)(ws + 786432 + 8388608);
    unsigned short* vb = (unsigned short*)(ws + 786432 + 2 * 8388608);

    prep_wt<<<384, 256, 0, stream>>>(Wq, Wk, Wv, wt);
    qkv_gemm<<<256, 512, 0, stream>>>(x, wt, qb, kb, vb);
    attn<<<256, 512, 0, stream>>>(qb, kb, vb, out);
}